// Round 1
// baseline (13924.277 us; speedup 1.0000x reference)
//
#include <hip/hip_runtime.h>
#include <math.h>

#define HH 64
#define WW 64
#define NB 8
#define CIN 32
#define COUT 32
#define NT 50
#define TILE 16
#define HALO 18   // TILE+2
#define CPAD 36   // padded channel stride in LDS (multiple of 4 -> 16B-aligned float4)
#define HW (HH*WW)

__device__ __forceinline__ float fsigmoid(float x) {
    return 1.0f / (1.0f + __expf(-x));
}
__device__ __forceinline__ float ftanh(float x) {
    float e = __expf(-2.0f * fabsf(x));
    float t = (1.0f - e) / (1.0f + e);
    return copysignf(t, x);
}

// W[oc][ci][3][3] -> Wt[(ci*9+k)][oc]  (makes inner-loop weight reads contiguous in oc)
__global__ __launch_bounds__(256) void wtrans(
    const float* __restrict__ Wx, const float* __restrict__ Wy, const float* __restrict__ Wz,
    float* __restrict__ Wxt, float* __restrict__ Wyt, float* __restrict__ Wzt)
{
    int i = blockIdx.x * 256 + threadIdx.x;
    if (i < 128*288) { int oc = i/288, r = i - oc*288; Wxt[r*128 + oc] = Wx[i]; }
    if (i <  96*288) { int oc = i/288, r = i - oc*288; Wyt[r*96  + oc] = Wy[i]; }
    if (i <  32*288) { int oc = i/288, r = i - oc*288; Wzt[r*32  + oc] = Wz[i]; }
}

// Kernel A: xconv (4 gates) + yconv (3 gates) + Z update; writes Z (in place), ms2, xy
__global__ __launch_bounds__(256) void lem_gates(
    const float* __restrict__ X,
    const float* __restrict__ Wxt, const float* __restrict__ bx,
    const float* __restrict__ Wyt, const float* __restrict__ by,
    const float* __restrict__ Y, float* __restrict__ Z,
    float* __restrict__ ms2w, float* __restrict__ xyw, int t)
{
    __shared__ __align__(16) float tile[HALO*HALO*CPAD];
    const int tid = threadIdx.x;
    const int tx = tid & 15, ty = tid >> 4;
    const int w0 = blockIdx.x * TILE, h0 = blockIdx.y * TILE;
    const int b  = blockIdx.z >> 3;
    const int c0 = (blockIdx.z & 7) * 4;

    // ---- stage x_t tile: X[b, ci, t, gh, gw] ----
    {
        const float* xb = X + ((size_t)b*CIN*NT + t) * HW;
        for (int idx = tid; idx < HALO*HALO*CIN; idx += 256) {
            int ci = idx / (HALO*HALO);
            int pix = idx - ci*(HALO*HALO);
            int r = pix / HALO, cc = pix - r*HALO;
            int gh = h0 + r - 1, gw = w0 + cc - 1;
            float v = 0.0f;
            if ((unsigned)gh < HH && (unsigned)gw < WW)
                v = xb[(size_t)ci*(NT*HW) + gh*WW + gw];
            tile[pix*CPAD + ci] = v;
        }
    }
    __syncthreads();

    float ax[16];  // [gate g 0..3][ch 0..3] -> ax[g*4+ch]
    #pragma unroll
    for (int i=0;i<16;i++) ax[i]=0.0f;

    for (int k=0;k<9;k++) {
        int kh = k/3, kw = k - kh*3;
        const float* lp = &tile[((ty+kh)*HALO + tx+kw)*CPAD];
        const float* wp = Wxt + (size_t)k*128 + c0;
        #pragma unroll
        for (int ci4=0; ci4<8; ci4++) {
            float4 xv = *(const float4*)(lp + ci4*4);
            #pragma unroll
            for (int j=0;j<4;j++) {
                float v = (j==0)?xv.x:(j==1)?xv.y:(j==2)?xv.z:xv.w;
                const float* wr = wp + (size_t)(ci4*4+j)*(9*128);
                #pragma unroll
                for (int g=0; g<4; g++) {
                    float4 wg = *(const float4*)(wr + g*32);
                    ax[g*4+0] = fmaf(v, wg.x, ax[g*4+0]);
                    ax[g*4+1] = fmaf(v, wg.y, ax[g*4+1]);
                    ax[g*4+2] = fmaf(v, wg.z, ax[g*4+2]);
                    ax[g*4+3] = fmaf(v, wg.w, ax[g*4+3]);
                }
            }
        }
    }
    __syncthreads();

    // ---- stage Y tile (reuse LDS) ----
    {
        const float* yb = Y + (size_t)b*COUT*HW;
        for (int idx = tid; idx < HALO*HALO*CIN; idx += 256) {
            int ci = idx / (HALO*HALO);
            int pix = idx - ci*(HALO*HALO);
            int r = pix / HALO, cc = pix - r*HALO;
            int gh = h0 + r - 1, gw = w0 + cc - 1;
            float v = 0.0f;
            if ((unsigned)gh < HH && (unsigned)gw < WW)
                v = yb[(size_t)ci*HW + gh*WW + gw];
            tile[pix*CPAD + ci] = v;
        }
    }
    __syncthreads();

    float ay[12];  // [gate 0..2][ch] -> ay[g*4+ch]
    #pragma unroll
    for (int i=0;i<12;i++) ay[i]=0.0f;

    for (int k=0;k<9;k++) {
        int kh = k/3, kw = k - kh*3;
        const float* lp = &tile[((ty+kh)*HALO + tx+kw)*CPAD];
        const float* wp = Wyt + (size_t)k*96 + c0;
        #pragma unroll
        for (int ci4=0; ci4<8; ci4++) {
            float4 xv = *(const float4*)(lp + ci4*4);
            #pragma unroll
            for (int j=0;j<4;j++) {
                float v = (j==0)?xv.x:(j==1)?xv.y:(j==2)?xv.z:xv.w;
                const float* wr = wp + (size_t)(ci4*4+j)*(9*96);
                #pragma unroll
                for (int g=0; g<3; g++) {
                    float4 wg = *(const float4*)(wr + g*32);
                    ay[g*4+0] = fmaf(v, wg.x, ay[g*4+0]);
                    ay[g*4+1] = fmaf(v, wg.y, ay[g*4+1]);
                    ay[g*4+2] = fmaf(v, wg.z, ay[g*4+2]);
                    ay[g*4+3] = fmaf(v, wg.w, ay[g*4+3]);
                }
            }
        }
    }

    // ---- pointwise: Z update + stash ms2/xy ----
    const int h = h0 + ty, w = w0 + tx;
    #pragma unroll
    for (int ch=0; ch<4; ch++) {
        int c = c0 + ch;
        size_t si = ((size_t)(b*COUT + c))*HW + h*WW + w;
        float g1 = ax[0*4+ch] + bx[c]        + ay[0*4+ch] + by[c];
        float g2 = ax[1*4+ch] + bx[COUT+c]   + ay[1*4+ch] + by[COUT+c];
        float zc = ax[2*4+ch] + bx[2*COUT+c] + ay[2*4+ch] + by[2*COUT+c];
        float xy = ax[3*4+ch] + bx[3*COUT+c];
        float m1 = fsigmoid(g1);
        float zn = (1.0f - m1) * Z[si] + m1 * ftanh(zc);
        Z[si]   = zn;
        ms2w[si] = fsigmoid(g2);
        xyw[si]  = xy;
    }
}

// Kernel B: conv(Z_new, Wz) + Y update; writes Y (in place) and out[:, :, t]
__global__ __launch_bounds__(256) void lem_update(
    const float* __restrict__ Wzt, const float* __restrict__ bz,
    const float* __restrict__ Z, float* __restrict__ Y,
    const float* __restrict__ ms2w, const float* __restrict__ xyw,
    float* __restrict__ out, int t)
{
    __shared__ __align__(16) float tile[HALO*HALO*CPAD];
    const int tid = threadIdx.x;
    const int tx = tid & 15, ty = tid >> 4;
    const int w0 = blockIdx.x * TILE, h0 = blockIdx.y * TILE;
    const int b  = blockIdx.z >> 3;
    const int c0 = (blockIdx.z & 7) * 4;

    {
        const float* zb = Z + (size_t)b*COUT*HW;
        for (int idx = tid; idx < HALO*HALO*CIN; idx += 256) {
            int ci = idx / (HALO*HALO);
            int pix = idx - ci*(HALO*HALO);
            int r = pix / HALO, cc = pix - r*HALO;
            int gh = h0 + r - 1, gw = w0 + cc - 1;
            float v = 0.0f;
            if ((unsigned)gh < HH && (unsigned)gw < WW)
                v = zb[(size_t)ci*HW + gh*WW + gw];
            tile[pix*CPAD + ci] = v;
        }
    }
    __syncthreads();

    float az[4] = {0.f,0.f,0.f,0.f};
    for (int k=0;k<9;k++) {
        int kh = k/3, kw = k - kh*3;
        const float* lp = &tile[((ty+kh)*HALO + tx+kw)*CPAD];
        const float* wp = Wzt + (size_t)k*32 + c0;
        #pragma unroll
        for (int ci4=0; ci4<8; ci4++) {
            float4 xv = *(const float4*)(lp + ci4*4);
            #pragma unroll
            for (int j=0;j<4;j++) {
                float v = (j==0)?xv.x:(j==1)?xv.y:(j==2)?xv.z:xv.w;
                float4 wg = *(const float4*)(wp + (size_t)(ci4*4+j)*(9*32));
                az[0] = fmaf(v, wg.x, az[0]);
                az[1] = fmaf(v, wg.y, az[1]);
                az[2] = fmaf(v, wg.z, az[2]);
                az[3] = fmaf(v, wg.w, az[3]);
            }
        }
    }

    const int h = h0 + ty, w = w0 + tx;
    #pragma unroll
    for (int ch=0; ch<4; ch++) {
        int c = c0 + ch;
        size_t si = ((size_t)(b*COUT + c))*HW + h*WW + w;
        float m2 = ms2w[si];
        float yn = (1.0f - m2) * Y[si] + m2 * ftanh(xyw[si] + az[ch] + bz[c]);
        Y[si] = yn;
        out[((size_t)(b*COUT + c)*NT + t)*HW + h*WW + w] = yn;
    }
}

extern "C" void kernel_launch(void* const* d_in, const int* in_sizes, int n_in,
                              void* d_out, int out_size, void* d_ws, size_t ws_size,
                              hipStream_t stream)
{
    const float* X  = (const float*)d_in[0];
    const float* Wx = (const float*)d_in[1];
    const float* bx = (const float*)d_in[2];
    const float* Wy = (const float*)d_in[3];
    const float* by = (const float*)d_in[4];
    const float* Wz = (const float*)d_in[5];
    const float* bz = (const float*)d_in[6];
    float* out = (float*)d_out;
    float* ws  = (float*)d_ws;

    const size_t S = (size_t)NB*COUT*HW;  // 1,048,576 elems per state tensor
    float* Y   = ws;
    float* Z   = ws + S;
    float* m2w = ws + 2*S;
    float* xyw = ws + 3*S;
    float* Wxt = ws + 4*S;
    float* Wyt = Wxt + 128*288;
    float* Wzt = Wyt + 96*288;

    // Y0 = Z0 = 0 (ws is poisoned with 0xAA before every timed call)
    hipMemsetAsync(Y, 0, 2*S*sizeof(float), stream);
    wtrans<<<dim3(144), dim3(256), 0, stream>>>(Wx, Wy, Wz, Wxt, Wyt, Wzt);

    dim3 grid(WW/TILE, HH/TILE, NB*8);
    for (int t = 0; t < NT; t++) {
        lem_gates <<<grid, 256, 0, stream>>>(X, Wxt, bx, Wyt, by, Y, Z, m2w, xyw, t);
        lem_update<<<grid, 256, 0, stream>>>(Wzt, bz, Z, Y, m2w, xyw, out, t);
    }
}